// Round 2
// baseline (5523.512 us; speedup 1.0000x reference)
//
#include <hip/hip_runtime.h>
#include <hip/hip_bf16.h>
#include <math.h>

#define HALF 64
#define LN_EPS 1e-5f

// ---------------------------------------------------------------------------
// Kernel 1: per-edge  rel -> normalize -> Linear(3,64) -> LN -> GELU(exact)
// then atomically accumulate post-GELU h into hagg[dst] and count deg[dst].
// (h @ W2 + b2) is deferred to the per-node epilogue since it's linear:
//   sum_e (h_e @ W2 + b2) = (sum_e h_e) @ W2 + deg * b2
// ---------------------------------------------------------------------------
__global__ void __launch_bounds__(256) edge_kernel(
    const float* __restrict__ pos,    // [N,3] fp32
    const int* __restrict__ ei,       // [2,E]
    const float* __restrict__ W1,     // [3,64]
    const float* __restrict__ b1,     // [64]
    const float* __restrict__ ln_g,   // [64]
    const float* __restrict__ ln_b,   // [64]
    float* __restrict__ hagg,         // [N,64] fp32 accum (pre-zeroed)
    float* __restrict__ deg,          // [N]    fp32 accum (pre-zeroed)
    int E)
{
    __shared__ float sW1[3 * HALF];
    __shared__ float sb1[HALF], sg[HALF], sb[HALF];
    const int tid = threadIdx.x;
    if (tid < HALF) {
        sW1[tid]            = W1[tid];
        sW1[HALF + tid]     = W1[HALF + tid];
        sW1[2 * HALF + tid] = W1[2 * HALF + tid];
        sb1[tid] = b1[tid];
        sg[tid]  = ln_g[tid];
        sb[tid]  = ln_b[tid];
    }
    __syncthreads();

    const int e = blockIdx.x * 256 + tid;
    if (e >= E) return;

    const int s = ei[e];
    const int d = ei[E + e];

    const float rx0 = pos[3 * d + 0] - pos[3 * s + 0];
    const float ry0 = pos[3 * d + 1] - pos[3 * s + 1];
    const float rz0 = pos[3 * d + 2] - pos[3 * s + 2];
    const float dist = sqrtf(rx0 * rx0 + ry0 * ry0 + rz0 * rz0);
    const float inv  = 1.0f / (dist + 1e-6f);
    const float rx = rx0 * inv, ry = ry0 * inv, rz = rz0 * inv;

    float h[HALF];
    float mu = 0.0f;
#pragma unroll
    for (int k = 0; k < HALF; ++k) {
        float v = fmaf(rx, sW1[k], fmaf(ry, sW1[HALF + k], fmaf(rz, sW1[2 * HALF + k], sb1[k])));
        h[k] = v;
        mu += v;
    }
    mu *= (1.0f / HALF);
    float var = 0.0f;
#pragma unroll
    for (int k = 0; k < HALF; ++k) {
        float c = h[k] - mu;
        var += c * c;
    }
    var *= (1.0f / HALF);
    const float rstd = rsqrtf(var + LN_EPS);

    float* hrow = hagg + (size_t)d * HALF;
#pragma unroll
    for (int k = 0; k < HALF; ++k) {
        float x = fmaf((h[k] - mu) * rstd, sg[k], sb[k]);
        // exact GELU: 0.5*x*(1+erf(x/sqrt(2)))
        x = 0.5f * x * (1.0f + erff(x * 0.70710678118654752f));
        unsafeAtomicAdd(&hrow[k], x);   // HW global_atomic_add_f32
    }
    unsafeAtomicAdd(&deg[d], 1.0f);
}

// ---------------------------------------------------------------------------
// Kernel 2: per-node epilogue.  out[n, 0:64] = (hagg[n] @ W2)/deg + b2
// (zero when deg==0), out[n, 64:128] = 0.  One wave per node, lane = out chan.
// ---------------------------------------------------------------------------
__global__ void __launch_bounds__(256) node_kernel(
    const float* __restrict__ hagg,   // [N,64]
    const float* __restrict__ deg,    // [N]
    const float* __restrict__ W2,     // [64,64]
    const float* __restrict__ b2,     // [64]
    float* __restrict__ out,          // [N,128] fp32
    int N)
{
    __shared__ float sW2[HALF * HALF];
    __shared__ float sb2[HALF];
    const int tid = threadIdx.x;
    for (int i = tid; i < HALF * HALF; i += 256) sW2[i] = W2[i];
    if (tid < HALF) sb2[tid] = b2[tid];
    __syncthreads();

    const int lane = tid & 63;
    const int n = blockIdx.x * 4 + (tid >> 6);
    if (n >= N) return;

    const float hv = hagg[(size_t)n * HALF + lane];
    const float dg = deg[n];

    float acc = 0.0f;
#pragma unroll
    for (int k = 0; k < HALF; ++k) {
        const float hk = __shfl(hv, k, 64);          // broadcast hagg[n][k]
        acc = fmaf(hk, sW2[k * HALF + lane], acc);   // 2 lanes/bank: conflict-free
    }

    const float r = (dg > 0.0f) ? (acc / dg + sb2[lane]) : 0.0f;
    float* orow = out + (size_t)n * (2 * HALF);
    orow[lane]        = r;
    orow[HALF + lane] = 0.0f;
}

// ---------------------------------------------------------------------------
extern "C" void kernel_launch(void* const* d_in, const int* in_sizes, int n_in,
                              void* d_out, int out_size, void* d_ws, size_t ws_size,
                              hipStream_t stream) {
    const float* pos = (const float*)d_in[0];
    const int*   ei  = (const int*)d_in[1];
    // d_in[2] = batch (unused)
    const float* W1  = (const float*)d_in[3];
    const float* b1  = (const float*)d_in[4];
    const float* g   = (const float*)d_in[5];
    const float* b   = (const float*)d_in[6];
    const float* W2  = (const float*)d_in[7];
    const float* b2  = (const float*)d_in[8];
    float* out = (float*)d_out;

    const int N = in_sizes[0] / 3;
    const int E = in_sizes[1] / 2;

    float* hagg = (float*)d_ws;
    float* degw = hagg + (size_t)N * HALF;
    const size_t zero_bytes = ((size_t)N * HALF + (size_t)N) * sizeof(float);
    hipMemsetAsync(d_ws, 0, zero_bytes, stream);

    edge_kernel<<<(E + 255) / 256, 256, 0, stream>>>(pos, ei, W1, b1, g, b, hagg, degw, E);
    node_kernel<<<(N + 3) / 4, 256, 0, stream>>>(hagg, degw, W2, b2, out, N);
}

// Round 3
// 574.314 us; speedup vs baseline: 9.6176x; 9.6176x over previous
//
#include <hip/hip_runtime.h>
#include <hip/hip_bf16.h>
#include <math.h>

#define HALF 64
#define LN_EPS 1e-5f

// ---------------------------------------------------------------------------
// K0: analytic-LN constants from W1 [3,64], b1 [64]  (1 wave, runs once)
// mu(r)   = u·r + c
// E[v^2]  = r^T G r + 2 p·r + q      (v = r·W1 + b1, mean over 64 channels)
// fp[0..13] = ux,uy,uz,c, Gxx,Gxy,Gxz,Gyy,Gyz,Gzz, px,py,pz,q
// ---------------------------------------------------------------------------
__global__ void __launch_bounds__(64) params_kernel(
    const float* __restrict__ W1, const float* __restrict__ b1,
    float* __restrict__ fp)
{
    const int k = threadIdx.x;
    const float w0 = W1[k], w1 = W1[HALF + k], w2 = W1[2 * HALF + k], b = b1[k];
    float v[14] = { w0, w1, w2, b,
                    w0 * w0, w0 * w1, w0 * w2, w1 * w1, w1 * w2, w2 * w2,
                    w0 * b, w1 * b, w2 * b, b * b };
#pragma unroll
    for (int j = 0; j < 14; ++j) {
        float s = v[j];
#pragma unroll
        for (int off = 32; off; off >>= 1) s += __shfl_down(s, off, 64);
        if (k == 0) fp[j] = s * (1.0f / 64.0f);
    }
}

// ---------------------------------------------------------------------------
// CSR build: histogram -> scan -> fill
// ---------------------------------------------------------------------------
__global__ void __launch_bounds__(256) hist_kernel(
    const int* __restrict__ ei, int* __restrict__ cursor, int E)
{
    const int e = blockIdx.x * 256 + threadIdx.x;
    if (e < E) atomicAdd(&cursor[ei[E + e]], 1);
}

// block b sums counts[b*1024 .. b*1024+1024) -> partials[b]
__global__ void __launch_bounds__(256) scan1_kernel(
    const int* __restrict__ cnt, int* __restrict__ partials, int N)
{
    __shared__ int lds[256];
    const int base = blockIdx.x * 1024 + threadIdx.x * 4;
    int s = 0;
#pragma unroll
    for (int j = 0; j < 4; ++j) {
        const int i = base + j;
        s += (i < N) ? cnt[i] : 0;
    }
    lds[threadIdx.x] = s;
    __syncthreads();
    for (int off = 128; off; off >>= 1) {
        if (threadIdx.x < off) lds[threadIdx.x] += lds[threadIdx.x + off];
        __syncthreads();
    }
    if (threadIdx.x == 0) partials[blockIdx.x] = lds[0];
}

// exclusive scan of partials[nb], nb <= 128, single block of 128 threads
__global__ void __launch_bounds__(128) scan2_kernel(int* __restrict__ partials, int nb)
{
    __shared__ int lds[128];
    const int t = threadIdx.x;
    const int v = (t < nb) ? partials[t] : 0;
    lds[t] = v;
    __syncthreads();
    for (int off = 1; off < 128; off <<= 1) {
        const int add = (t >= off) ? lds[t - off] : 0;
        __syncthreads();
        lds[t] += add;
        __syncthreads();
    }
    if (t < nb) partials[t] = lds[t] - v;   // exclusive
}

// full exclusive scan: cursor(counts) -> offsets; also cursor <- offsets (fill cursors)
__global__ void __launch_bounds__(256) scan3_kernel(
    int* __restrict__ cursor, int* __restrict__ offsets,
    const int* __restrict__ partials, int N)
{
    __shared__ int lds[256];
    const int base = blockIdx.x * 1024 + threadIdx.x * 4;
    int vals[4];
    int s = 0;
#pragma unroll
    for (int j = 0; j < 4; ++j) {
        const int i = base + j;
        const int c = (i < N) ? cursor[i] : 0;
        vals[j] = s;            // local exclusive prefix
        s += c;
    }
    lds[threadIdx.x] = s;
    __syncthreads();
    for (int off = 1; off < 256; off <<= 1) {
        const int add = (threadIdx.x >= off) ? lds[threadIdx.x - off] : 0;
        __syncthreads();
        lds[threadIdx.x] += add;
        __syncthreads();
    }
    const int tpre = lds[threadIdx.x] - s;      // exclusive across block
    const int bofs = partials[blockIdx.x];
#pragma unroll
    for (int j = 0; j < 4; ++j) {
        const int i = base + j;
        if (i <= N) {
            const int o = bofs + tpre + vals[j];
            offsets[i] = o;
            if (i < N) cursor[i] = o;           // cursor becomes fill pointer
        }
    }
}

__global__ void __launch_bounds__(256) fill_kernel(
    const int* __restrict__ ei, int* __restrict__ cursor,
    int* __restrict__ src_perm, int E)
{
    const int e = blockIdx.x * 256 + threadIdx.x;
    if (e >= E) return;
    const int d = ei[E + e];
    const int s = ei[e];
    const int slot = atomicAdd(&cursor[d], 1);
    src_perm[slot] = s;
}

// ---------------------------------------------------------------------------
// Fused node kernel: wave per node, lane = channel.
// Walk incoming edges, per-edge pipeline with analytic LN (no cross-lane),
// accumulate post-GELU h in a register; epilogue = (acc @ W2)/deg + b2.
// ---------------------------------------------------------------------------
__global__ void __launch_bounds__(256) node_kernel(
    const float* __restrict__ pos,        // [N,3]
    const int* __restrict__ src_perm,     // [E]
    const int* __restrict__ offsets,      // [N+1]
    const float* __restrict__ W1,         // [3,64]
    const float* __restrict__ b1,
    const float* __restrict__ ln_g,
    const float* __restrict__ ln_b,
    const float* __restrict__ W2,         // [64,64]
    const float* __restrict__ b2,
    const float* __restrict__ fp,         // [14] analytic-LN constants
    float* __restrict__ out,              // [N,128]
    int N)
{
    __shared__ float sW2[HALF * HALF];
    __shared__ float sb2[HALF];
    const int tid = threadIdx.x;
    for (int i = tid; i < HALF * HALF; i += 256) sW2[i] = W2[i];
    if (tid < HALF) sb2[tid] = b2[tid];
    __syncthreads();

    const int lane = tid & 63;
    const int n = blockIdx.x * 4 + (tid >> 6);
    if (n >= N) return;

    // per-lane channel params
    const float w0 = W1[lane], w1 = W1[HALF + lane], w2 = W1[2 * HALF + lane];
    const float bb = b1[lane], gl = ln_g[lane], bl = ln_b[lane];
    // analytic-LN constants (broadcast loads)
    const float ux = fp[0], uy = fp[1], uz = fp[2], c1 = fp[3];
    const float Gxx = fp[4], Gxy = fp[5], Gxz = fp[6];
    const float Gyy = fp[7], Gyz = fp[8], Gzz = fp[9];
    const float ppx = fp[10], ppy = fp[11], ppz = fp[12], qq = fp[13];

    const int beg = offsets[n];
    const int end = offsets[n + 1];
    const float pnx = pos[3 * n + 0], pny = pos[3 * n + 1], pnz = pos[3 * n + 2];

    float acc = 0.0f;
    for (int i = beg; i < end; ++i) {
        const int s = src_perm[i];
        const float rx0 = pnx - pos[3 * s + 0];
        const float ry0 = pny - pos[3 * s + 1];
        const float rz0 = pnz - pos[3 * s + 2];
        const float dist = sqrtf(rx0 * rx0 + ry0 * ry0 + rz0 * rz0);
        const float inv = 1.0f / (dist + 1e-6f);
        const float rx = rx0 * inv, ry = ry0 * inv, rz = rz0 * inv;

        const float mu = fmaf(ux, rx, fmaf(uy, ry, fmaf(uz, rz, c1)));
        const float ev2 = Gxx * rx * rx + Gyy * ry * ry + Gzz * rz * rz
                        + 2.0f * (Gxy * rx * ry + Gxz * rx * rz + Gyz * ry * rz
                                  + ppx * rx + ppy * ry + ppz * rz) + qq;
        const float var = ev2 - mu * mu;
        const float rstd = rsqrtf(var + LN_EPS);

        const float v = fmaf(rx, w0, fmaf(ry, w1, fmaf(rz, w2, bb)));
        float x = fmaf((v - mu) * rstd, gl, bl);
        x = 0.5f * x * (1.0f + erff(x * 0.70710678118654752f));   // exact GELU
        acc += x;
    }

    // deferred second linear: out = (acc @ W2)/deg + b2
    float o = 0.0f;
#pragma unroll
    for (int k = 0; k < HALF; ++k) {
        const float hk = __shfl(acc, k, 64);
        o = fmaf(hk, sW2[k * HALF + lane], o);   // 2 lanes/bank: conflict-free
    }
    const int deg = end - beg;
    const float r = (deg > 0) ? (o / (float)deg + sb2[lane]) : 0.0f;
    float* orow = out + (size_t)n * (2 * HALF);
    orow[lane] = r;
    orow[HALF + lane] = 0.0f;
}

// ---------------------------------------------------------------------------
extern "C" void kernel_launch(void* const* d_in, const int* in_sizes, int n_in,
                              void* d_out, int out_size, void* d_ws, size_t ws_size,
                              hipStream_t stream) {
    const float* pos = (const float*)d_in[0];
    const int*   ei  = (const int*)d_in[1];
    // d_in[2] = batch (unused)
    const float* W1  = (const float*)d_in[3];
    const float* b1  = (const float*)d_in[4];
    const float* g   = (const float*)d_in[5];
    const float* b   = (const float*)d_in[6];
    const float* W2  = (const float*)d_in[7];
    const float* b2  = (const float*)d_in[8];
    float* out = (float*)d_out;

    const int N = in_sizes[0] / 3;
    const int E = in_sizes[1] / 2;

    // workspace layout (ints then floats), ~7.3 MB total
    int* cursor   = (int*)d_ws;            // [N]   counts -> fill pointers
    int* offsets  = cursor + N + 64;       // [N+1]
    int* partials = offsets + N + 64;      // [128]
    int* src_perm = partials + 128;        // [E]
    float* fparams = (float*)(src_perm + E); // [14]

    const int nb = (N + 1023) / 1024;      // 98 for N=100k (must be <= 128)

    hipMemsetAsync(cursor, 0, (size_t)N * sizeof(int), stream);
    params_kernel<<<1, 64, 0, stream>>>(W1, b1, fparams);
    hist_kernel<<<(E + 255) / 256, 256, 0, stream>>>(ei, cursor, E);
    scan1_kernel<<<nb, 256, 0, stream>>>(cursor, partials, N);
    scan2_kernel<<<1, 128, 0, stream>>>(partials, nb);
    scan3_kernel<<<nb, 256, 0, stream>>>(cursor, offsets, partials, N);
    fill_kernel<<<(E + 255) / 256, 256, 0, stream>>>(ei, cursor, src_perm, E);
    node_kernel<<<(N + 3) / 4, 256, 0, stream>>>(pos, src_perm, offsets,
                                                 W1, b1, g, b, W2, b2, fparams,
                                                 out, N);
}

// Round 4
// 402.001 us; speedup vs baseline: 13.7401x; 1.4286x over previous
//
#include <hip/hip_runtime.h>
#include <math.h>

#define HALF 64
#define LN_EPS 1e-5f

// gelu_tanh(x) = x * sigmoid(1.5957691*x + 0.0713549*x^3)
// e^{-2y} = exp2(x*(GC1*x^2 + GC0))
#define GC0 -2.3022082f
#define GC1 -0.1029438f

// ---------------------------------------------------------------------------
// K0: analytic-LN constants from W1 [3,64], b1 [64]  (1 wave, runs once)
// mu(r) = u.r + c ;  E[v^2] = r^T G r + 2 p.r + q   (v = r.W1 + b1)
// fp[0..13] = ux,uy,uz,c, Gxx,Gxy,Gxz,Gyy,Gyz,Gzz, px,py,pz,q
// ---------------------------------------------------------------------------
__global__ void __launch_bounds__(64) params_kernel(
    const float* __restrict__ W1, const float* __restrict__ b1,
    float* __restrict__ fp)
{
    const int k = threadIdx.x;
    const float w0 = W1[k], w1 = W1[HALF + k], w2 = W1[2 * HALF + k], b = b1[k];
    float v[14] = { w0, w1, w2, b,
                    w0 * w0, w0 * w1, w0 * w2, w1 * w1, w1 * w2, w2 * w2,
                    w0 * b, w1 * b, w2 * b, b * b };
#pragma unroll
    for (int j = 0; j < 14; ++j) {
        float s = v[j];
#pragma unroll
        for (int off = 32; off; off >>= 1) s += __shfl_down(s, off, 64);
        if (k == 0) fp[j] = s * (1.0f / 64.0f);
    }
}

// ---------------------------------------------------------------------------
// CSR build: histogram -> scan -> fill(+geometry)
// ---------------------------------------------------------------------------
__global__ void __launch_bounds__(256) hist_kernel(
    const int* __restrict__ dst, int* __restrict__ cursor, int E)
{
    const int i = blockIdx.x * 256 + threadIdx.x;       // quad index
    const int e4 = i * 4;
    if (e4 + 3 < E) {
        const int4 d = *(const int4*)(dst + e4);
        atomicAdd(&cursor[d.x], 1);
        atomicAdd(&cursor[d.y], 1);
        atomicAdd(&cursor[d.z], 1);
        atomicAdd(&cursor[d.w], 1);
    } else {
        for (int e = e4; e < E; ++e) atomicAdd(&cursor[dst[e]], 1);
    }
}

__global__ void __launch_bounds__(256) scan1_kernel(
    const int* __restrict__ cnt, int* __restrict__ partials, int N)
{
    __shared__ int lds[256];
    const int base = blockIdx.x * 1024 + threadIdx.x * 4;
    int s = 0;
#pragma unroll
    for (int j = 0; j < 4; ++j) {
        const int i = base + j;
        s += (i < N) ? cnt[i] : 0;
    }
    lds[threadIdx.x] = s;
    __syncthreads();
    for (int off = 128; off; off >>= 1) {
        if (threadIdx.x < off) lds[threadIdx.x] += lds[threadIdx.x + off];
        __syncthreads();
    }
    if (threadIdx.x == 0) partials[blockIdx.x] = lds[0];
}

__global__ void __launch_bounds__(128) scan2_kernel(int* __restrict__ partials, int nb)
{
    __shared__ int lds[128];
    const int t = threadIdx.x;
    const int v = (t < nb) ? partials[t] : 0;
    lds[t] = v;
    __syncthreads();
    for (int off = 1; off < 128; off <<= 1) {
        const int add = (t >= off) ? lds[t - off] : 0;
        __syncthreads();
        lds[t] += add;
        __syncthreads();
    }
    if (t < nb) partials[t] = lds[t] - v;   // exclusive
}

__global__ void __launch_bounds__(256) scan3_kernel(
    int* __restrict__ cursor, int* __restrict__ offsets,
    const int* __restrict__ partials, int N)
{
    __shared__ int lds[256];
    const int base = blockIdx.x * 1024 + threadIdx.x * 4;
    int vals[4];
    int s = 0;
#pragma unroll
    for (int j = 0; j < 4; ++j) {
        const int i = base + j;
        const int c = (i < N) ? cursor[i] : 0;
        vals[j] = s;
        s += c;
    }
    lds[threadIdx.x] = s;
    __syncthreads();
    for (int off = 1; off < 256; off <<= 1) {
        const int add = (threadIdx.x >= off) ? lds[threadIdx.x - off] : 0;
        __syncthreads();
        lds[threadIdx.x] += add;
        __syncthreads();
    }
    const int tpre = lds[threadIdx.x] - s;
    const int bofs = partials[blockIdx.x];
#pragma unroll
    for (int j = 0; j < 4; ++j) {
        const int i = base + j;
        if (i <= N) {
            const int o = bofs + tpre + vals[j];
            offsets[i] = o;
            if (i < N) cursor[i] = o;       // cursor becomes fill pointer
        }
    }
}

// fill: per edge compute geometry ONCE, store A[slot]=(rx,ry,rz,1)*rstd in CSR order
__global__ void __launch_bounds__(256) fill_kernel(
    const int* __restrict__ ei, const float* __restrict__ pos,
    const float* __restrict__ fp, int* __restrict__ cursor,
    float4* __restrict__ A, int E)
{
    const int e = blockIdx.x * 256 + threadIdx.x;
    if (e >= E) return;
    const int s = ei[e];
    const int d = ei[E + e];

    const float rx0 = pos[3 * d + 0] - pos[3 * s + 0];
    const float ry0 = pos[3 * d + 1] - pos[3 * s + 1];
    const float rz0 = pos[3 * d + 2] - pos[3 * s + 2];
    const float dist = sqrtf(rx0 * rx0 + ry0 * ry0 + rz0 * rz0);
    const float inv  = 1.0f / (dist + 1e-6f);
    const float rx = rx0 * inv, ry = ry0 * inv, rz = rz0 * inv;

    const float mu  = fmaf(fp[0], rx, fmaf(fp[1], ry, fmaf(fp[2], rz, fp[3])));
    const float ev2 = fp[4] * rx * rx + fp[7] * ry * ry + fp[9] * rz * rz
                    + 2.0f * (fp[5] * rx * ry + fp[6] * rx * rz + fp[8] * ry * rz
                              + fp[10] * rx + fp[11] * ry + fp[12] * rz) + fp[13];
    const float rstd = rsqrtf(ev2 - mu * mu + LN_EPS);

    const int slot = atomicAdd(&cursor[d], 1);
    A[slot] = make_float4(rx * rstd, ry * rstd, rz * rstd, rstd);
}

// ---------------------------------------------------------------------------
// Node kernel: wave per node, lane = channel.
// x = C0*ax + C1*ay + C2*az + C3*aw + beta_l   (4 FMA, LN fully folded)
// gelu(x) = x*sigmoid(2y) via v_exp_f32 + v_rcp_f32.
// Epilogue: out = (acc @ W2)/deg + b2.
// ---------------------------------------------------------------------------
__global__ void __launch_bounds__(256) node_kernel(
    const float4* __restrict__ A,        // [E+4] CSR-ordered
    const int* __restrict__ offsets,     // [N+1]
    const float* __restrict__ W1, const float* __restrict__ b1,
    const float* __restrict__ ln_g, const float* __restrict__ ln_b,
    const float* __restrict__ W2, const float* __restrict__ b2,
    const float* __restrict__ fp,
    float* __restrict__ out, int N)
{
    __shared__ float sW2[HALF * HALF];
    __shared__ float sb2[HALF];
    const int tid = threadIdx.x;
    for (int i = tid; i < HALF * HALF; i += 256) sW2[i] = W2[i];
    if (tid < HALF) sb2[tid] = b2[tid];
    __syncthreads();

    const int lane = tid & 63;
    const int n = blockIdx.x * 4 + (tid >> 6);
    if (n >= N) return;

    const float gl = ln_g[lane];
    const float C0 = gl * (W1[lane]            - fp[0]);
    const float C1 = gl * (W1[HALF + lane]     - fp[1]);
    const float C2 = gl * (W1[2 * HALF + lane] - fp[2]);
    const float C3 = gl * (b1[lane]            - fp[3]);
    const float Bl = ln_b[lane];

    const int beg = offsets[n];
    const int end = offsets[n + 1];

    float acc = 0.0f;
    if (beg < end) {
        float4 a = A[beg];
        for (int i = beg; i < end; ++i) {
            const float4 an = A[i + 1];            // prefetch (A over-allocated)
            const float x  = fmaf(C0, a.x, fmaf(C1, a.y, fmaf(C2, a.z, fmaf(C3, a.w, Bl))));
            const float x2 = x * x;
            const float z  = x * fmaf(GC1, x2, GC0);
            const float e  = __builtin_amdgcn_exp2f(z);
            const float sg = __builtin_amdgcn_rcpf(1.0f + e);
            acc = fmaf(x, sg, acc);
            a = an;
        }
    }

    float o = 0.0f;
#pragma unroll
    for (int k = 0; k < HALF; ++k) {
        const float hk = __shfl(acc, k, 64);
        o = fmaf(hk, sW2[k * HALF + lane], o);
    }
    const int deg = end - beg;
    const float r = (deg > 0) ? (o / (float)deg + sb2[lane]) : 0.0f;
    float* orow = out + (size_t)n * (2 * HALF);
    orow[lane] = r;
    orow[HALF + lane] = 0.0f;
}

// ---------------------------------------------------------------------------
extern "C" void kernel_launch(void* const* d_in, const int* in_sizes, int n_in,
                              void* d_out, int out_size, void* d_ws, size_t ws_size,
                              hipStream_t stream) {
    const float* pos = (const float*)d_in[0];
    const int*   ei  = (const int*)d_in[1];
    // d_in[2] = batch (unused)
    const float* W1  = (const float*)d_in[3];
    const float* b1  = (const float*)d_in[4];
    const float* g   = (const float*)d_in[5];
    const float* b   = (const float*)d_in[6];
    const float* W2  = (const float*)d_in[7];
    const float* b2  = (const float*)d_in[8];
    float* out = (float*)d_out;

    const int N = in_sizes[0] / 3;
    const int E = in_sizes[1] / 2;

    // workspace: A[E+4] float4 | cursor[N] | offsets[N+1] | partials[128] | fp[14]
    float4* A      = (float4*)d_ws;
    int* cursor    = (int*)(A + E + 4);
    int* offsets   = cursor + N;
    int* partials  = offsets + N + 1;
    float* fparams = (float*)(partials + 128);

    const int nb = (N + 1023) / 1024;   // 98 for N=100k (<=128)

    hipMemsetAsync(cursor, 0, (size_t)N * sizeof(int), stream);
    params_kernel<<<1, 64, 0, stream>>>(W1, b1, fparams);
    hist_kernel<<<(E / 4 + 255) / 256, 256, 0, stream>>>(ei + E, cursor, E);
    scan1_kernel<<<nb, 256, 0, stream>>>(cursor, partials, N);
    scan2_kernel<<<1, 128, 0, stream>>>(partials, nb);
    scan3_kernel<<<nb, 256, 0, stream>>>(cursor, offsets, partials, N);
    fill_kernel<<<(E + 255) / 256, 256, 0, stream>>>(ei, pos, fparams, cursor, A, E);
    node_kernel<<<(N + 3) / 4, 256, 0, stream>>>(A, offsets, W1, b1, g, b, W2, b2,
                                                 fparams, out, N);
}

// Round 5
// 397.773 us; speedup vs baseline: 13.8861x; 1.0106x over previous
//
#include <hip/hip_runtime.h>
#include <math.h>

#define HALF 64
#define LN_EPS 1e-5f

// gelu_tanh(x) = x * sigmoid(1.5957691*x + 0.0713549*x^3)
// sigmoid via exp2: e = exp2(x*(GC1*x^2 + GC0)); g = x / (1+e)
#define GC0 -2.3022082f
#define GC1 -0.1029438f

__device__ __forceinline__ float gelu_fast(float x) {
    const float x2 = x * x;
    const float z  = x * fmaf(GC1, x2, GC0);
    const float e  = __builtin_amdgcn_exp2f(z);
    const float sg = __builtin_amdgcn_rcpf(1.0f + e);
    return x * sg;
}

// ---------------------------------------------------------------------------
// CSR build: histogram -> scan -> fill(+geometry)
// ---------------------------------------------------------------------------
__global__ void __launch_bounds__(256) hist_kernel(
    const int* __restrict__ dst, int* __restrict__ cursor, int E)
{
    const int e4 = (blockIdx.x * 256 + threadIdx.x) * 4;
    if (e4 + 3 < E) {
        const int4 d = *(const int4*)(dst + e4);
        atomicAdd(&cursor[d.x], 1);
        atomicAdd(&cursor[d.y], 1);
        atomicAdd(&cursor[d.z], 1);
        atomicAdd(&cursor[d.w], 1);
    } else {
        for (int e = e4; e < E; ++e) atomicAdd(&cursor[dst[e]], 1);
    }
}

__global__ void __launch_bounds__(256) scan1_kernel(
    const int* __restrict__ cnt, int* __restrict__ partials, int N)
{
    __shared__ int lds[256];
    const int base = blockIdx.x * 1024 + threadIdx.x * 4;
    int s = 0;
#pragma unroll
    for (int j = 0; j < 4; ++j) {
        const int i = base + j;
        s += (i < N) ? cnt[i] : 0;
    }
    lds[threadIdx.x] = s;
    __syncthreads();
    for (int off = 128; off; off >>= 1) {
        if (threadIdx.x < off) lds[threadIdx.x] += lds[threadIdx.x + off];
        __syncthreads();
    }
    if (threadIdx.x == 0) partials[blockIdx.x] = lds[0];
}

// scan2 + params fused: wave0 first computes analytic-LN constants (no
// barriers), then all 128 threads run the partials exclusive scan.
// fp[0..13] = ux,uy,uz,c, Gxx,Gxy,Gxz,Gyy,Gyz,Gzz, px,py,pz,q
__global__ void __launch_bounds__(128) scan2_params_kernel(
    int* __restrict__ partials, int nb,
    const float* __restrict__ W1, const float* __restrict__ b1,
    float* __restrict__ fp)
{
    const int t = threadIdx.x;
    if (t < 64) {
        const float w0 = W1[t], w1 = W1[HALF + t], w2 = W1[2 * HALF + t], b = b1[t];
        float v[14] = { w0, w1, w2, b,
                        w0 * w0, w0 * w1, w0 * w2, w1 * w1, w1 * w2, w2 * w2,
                        w0 * b, w1 * b, w2 * b, b * b };
#pragma unroll
        for (int j = 0; j < 14; ++j) {
            float s = v[j];
#pragma unroll
            for (int off = 32; off; off >>= 1) s += __shfl_down(s, off, 64);
            if (t == 0) fp[j] = s * (1.0f / 64.0f);
        }
    }
    __shared__ int lds[128];
    const int v = (t < nb) ? partials[t] : 0;
    lds[t] = v;
    __syncthreads();
    for (int off = 1; off < 128; off <<= 1) {
        const int add = (t >= off) ? lds[t - off] : 0;
        __syncthreads();
        lds[t] += add;
        __syncthreads();
    }
    if (t < nb) partials[t] = lds[t] - v;   // exclusive
}

__global__ void __launch_bounds__(256) scan3_kernel(
    int* __restrict__ cursor, int* __restrict__ offsets,
    const int* __restrict__ partials, int N)
{
    __shared__ int lds[256];
    const int base = blockIdx.x * 1024 + threadIdx.x * 4;
    int vals[4];
    int s = 0;
#pragma unroll
    for (int j = 0; j < 4; ++j) {
        const int i = base + j;
        const int c = (i < N) ? cursor[i] : 0;
        vals[j] = s;
        s += c;
    }
    lds[threadIdx.x] = s;
    __syncthreads();
    for (int off = 1; off < 256; off <<= 1) {
        const int add = (threadIdx.x >= off) ? lds[threadIdx.x - off] : 0;
        __syncthreads();
        lds[threadIdx.x] += add;
        __syncthreads();
    }
    const int tpre = lds[threadIdx.x] - s;
    const int bofs = partials[blockIdx.x];
#pragma unroll
    for (int j = 0; j < 4; ++j) {
        const int i = base + j;
        if (i <= N) {
            const int o = bofs + tpre + vals[j];
            offsets[i] = o;
            if (i < N) cursor[i] = o;       // cursor becomes fill pointer
        }
    }
}

// fill: 4 edges/thread; per edge compute geometry ONCE,
// store A[slot]=(rx,ry,rz,1)*rstd grouped by dst.
__global__ void __launch_bounds__(256) fill_kernel(
    const int* __restrict__ ei, const float* __restrict__ pos,
    const float* __restrict__ fp, int* __restrict__ cursor,
    float4* __restrict__ A, int E)
{
    const int e4 = (blockIdx.x * 256 + threadIdx.x) * 4;
    if (e4 >= E) return;

    int se[4], de[4];
    if (e4 + 3 < E) {
        *(int4*)se = *(const int4*)(ei + e4);
        *(int4*)de = *(const int4*)(ei + E + e4);
    } else {
        for (int j = 0; j < 4; ++j) {
            const int e = e4 + j;
            se[j] = (e < E) ? ei[e] : 0;
            de[j] = (e < E) ? ei[E + e] : 0;
        }
    }
    const float ux = fp[0], uy = fp[1], uz = fp[2], cc = fp[3];
    const float Gxx = fp[4], Gxy = fp[5], Gxz = fp[6];
    const float Gyy = fp[7], Gyz = fp[8], Gzz = fp[9];
    const float px = fp[10], py = fp[11], pz = fp[12], qq = fp[13];

#pragma unroll
    for (int j = 0; j < 4; ++j) {
        const int e = e4 + j;
        if (e >= E) break;
        const int s = se[j], d = de[j];
        const float rx0 = pos[3 * d + 0] - pos[3 * s + 0];
        const float ry0 = pos[3 * d + 1] - pos[3 * s + 1];
        const float rz0 = pos[3 * d + 2] - pos[3 * s + 2];
        const float dist = sqrtf(rx0 * rx0 + ry0 * ry0 + rz0 * rz0);
        const float inv  = 1.0f / (dist + 1e-6f);
        const float rx = rx0 * inv, ry = ry0 * inv, rz = rz0 * inv;

        const float mu  = fmaf(ux, rx, fmaf(uy, ry, fmaf(uz, rz, cc)));
        const float ev2 = Gxx * rx * rx + Gyy * ry * ry + Gzz * rz * rz
                        + 2.0f * (Gxy * rx * ry + Gxz * rx * rz + Gyz * ry * rz
                                  + px * rx + py * ry + pz * rz) + qq;
        const float rstd = rsqrtf(ev2 - mu * mu + LN_EPS);

        const int slot = atomicAdd(&cursor[d], 1);
        A[slot] = make_float4(rx * rstd, ry * rstd, rz * rstd, rstd);
    }
}

// ---------------------------------------------------------------------------
// Node kernel: wave per node, lane = channel.
// x = C0*ax + C1*ay + C2*az + C3*aw + Bl   (LN fully folded into 4 FMA)
// K-loop: chunks of 4 edges, double-buffered (8 loads in flight, one
// vmcnt drain per 4 edges instead of per edge — latency-hiding fix).
// Epilogue: out = (acc @ W2)/deg + b2.
// ---------------------------------------------------------------------------
__global__ void __launch_bounds__(256) node_kernel(
    const float4* __restrict__ A,        // [E+8] CSR-ordered (padded)
    const int* __restrict__ offsets,     // [N+1]
    const float* __restrict__ W1, const float* __restrict__ b1,
    const float* __restrict__ ln_g, const float* __restrict__ ln_b,
    const float* __restrict__ W2, const float* __restrict__ b2,
    const float* __restrict__ fp,
    float* __restrict__ out, int N)
{
    __shared__ float sW2[HALF * HALF];
    __shared__ float sb2[HALF];
    const int tid = threadIdx.x;
    for (int i = tid; i < HALF * HALF; i += 256) sW2[i] = W2[i];
    if (tid < HALF) sb2[tid] = b2[tid];
    __syncthreads();

    const int lane = tid & 63;
    const int n = blockIdx.x * 4 + (tid >> 6);
    if (n >= N) return;

    const float gl = ln_g[lane];
    const float C0 = gl * (W1[lane]            - fp[0]);
    const float C1 = gl * (W1[HALF + lane]     - fp[1]);
    const float C2 = gl * (W1[2 * HALF + lane] - fp[2]);
    const float C3 = gl * (b1[lane]            - fp[3]);
    const float Bl = ln_b[lane];

    const int beg = offsets[n];
    const int end = offsets[n + 1];
    const int cnt = end - beg;

    float acc = 0.0f;
    if (cnt > 0) {
        const float4* Ap = A + beg;
        float4 a0 = Ap[0], a1 = Ap[1], a2 = Ap[2], a3 = Ap[3];   // pad-safe
        for (int i = 0; i < cnt; i += 4) {
            const float4 n0 = Ap[i + 4], n1 = Ap[i + 5],
                         n2 = Ap[i + 6], n3 = Ap[i + 7];         // prefetch
            const int rem = cnt - i;
            const float g0 = gelu_fast(fmaf(C0, a0.x, fmaf(C1, a0.y, fmaf(C2, a0.z, fmaf(C3, a0.w, Bl)))));
            const float g1 = gelu_fast(fmaf(C0, a1.x, fmaf(C1, a1.y, fmaf(C2, a1.z, fmaf(C3, a1.w, Bl)))));
            const float g2 = gelu_fast(fmaf(C0, a2.x, fmaf(C1, a2.y, fmaf(C2, a2.z, fmaf(C3, a2.w, Bl)))));
            const float g3 = gelu_fast(fmaf(C0, a3.x, fmaf(C1, a3.y, fmaf(C2, a3.z, fmaf(C3, a3.w, Bl)))));
            acc += g0;                                  // i < cnt always
            acc += (rem > 1) ? g1 : 0.0f;
            acc += (rem > 2) ? g2 : 0.0f;
            acc += (rem > 3) ? g3 : 0.0f;
            a0 = n0; a1 = n1; a2 = n2; a3 = n3;
        }
    }

    float o = 0.0f;
#pragma unroll
    for (int k = 0; k < HALF; ++k) {
        const float hk = __shfl(acc, k, 64);
        o = fmaf(hk, sW2[k * HALF + lane], o);
    }
    const float r = (cnt > 0) ? (o / (float)cnt + sb2[lane]) : 0.0f;
    float* orow = out + (size_t)n * (2 * HALF);
    orow[lane] = r;
    orow[HALF + lane] = 0.0f;
}

// ---------------------------------------------------------------------------
extern "C" void kernel_launch(void* const* d_in, const int* in_sizes, int n_in,
                              void* d_out, int out_size, void* d_ws, size_t ws_size,
                              hipStream_t stream) {
    const float* pos = (const float*)d_in[0];
    const int*   ei  = (const int*)d_in[1];
    // d_in[2] = batch (unused)
    const float* W1  = (const float*)d_in[3];
    const float* b1  = (const float*)d_in[4];
    const float* g   = (const float*)d_in[5];
    const float* b   = (const float*)d_in[6];
    const float* W2  = (const float*)d_in[7];
    const float* b2  = (const float*)d_in[8];
    float* out = (float*)d_out;

    const int N = in_sizes[0] / 3;
    const int E = in_sizes[1] / 2;

    // workspace: A[E+8] float4 | cursor[N] | offsets[N+1] | partials[128] | fp[14]
    float4* A      = (float4*)d_ws;
    int* cursor    = (int*)(A + E + 8);
    int* offsets   = cursor + N;
    int* partials  = offsets + N + 1;
    float* fparams = (float*)(partials + 128);

    const int nb = (N + 1023) / 1024;   // 98 for N=100k (<=128)

    hipMemsetAsync(cursor, 0, (size_t)N * sizeof(int), stream);
    hist_kernel<<<(E / 4 + 255) / 256, 256, 0, stream>>>(ei + E, cursor, E);
    scan1_kernel<<<nb, 256, 0, stream>>>(cursor, partials, N);
    scan2_params_kernel<<<1, 128, 0, stream>>>(partials, nb, W1, b1, fparams);
    scan3_kernel<<<nb, 256, 0, stream>>>(cursor, offsets, partials, N);
    fill_kernel<<<(E / 4 + 255) / 256, 256, 0, stream>>>(ei, pos, fparams, cursor, A, E);
    node_kernel<<<(N + 3) / 4, 256, 0, stream>>>(A, offsets, W1, b1, g, b, W2, b2,
                                                 fparams, out, N);
}